// Round 6
// baseline (265.803 us; speedup 1.0000x reference)
//
#include <hip/hip_runtime.h>
#include <hip/hip_bf16.h>

#define E_    8
#define D_    2048
#define H_    1024
#define T_    2048   // B*L tokens
#define BK    64

using u16   = unsigned short;
using s16x8 = __attribute__((ext_vector_type(8))) short;
using f32x4 = __attribute__((ext_vector_type(4))) float;

__device__ __forceinline__ short f2bf(float f) {
  __hip_bfloat16 h = __float2bfloat16(f);          // HW v_cvt (RNE), pairs fuse to cvt_pk
  return __builtin_bit_cast(short, h);
}
__device__ __forceinline__ s16x8 cvt8(f32x4 a, f32x4 b) {
  s16x8 o;
  o[0]=f2bf(a.x); o[1]=f2bf(a.y); o[2]=f2bf(a.z); o[3]=f2bf(a.w);
  o[4]=f2bf(b.x); o[5]=f2bf(b.y); o[6]=f2bf(b.z); o[7]=f2bf(b.w);
  return o;
}
// swizzled LDS slot (elem index) for (row, 8-elem chunk) in a [*][64] bf16 tile
__device__ __forceinline__ int slot(int r, int c) { return r * 64 + ((c ^ (r & 7)) << 3); }

__device__ __forceinline__ void gload16(const void* g, void* l) {
  __builtin_amdgcn_global_load_lds((const __attribute__((address_space(1))) void*)g,
                                   (__attribute__((address_space(3))) void*)l, 16, 0, 0);
}

// find (e, mt, Ne) for linear m-tile index ml; all static-indexed (registers only)
#define FIND_EXPERT(ml, cnt, e, mt, Ne)                        \
  { int b_ = 0;                                                \
    _Pragma("unroll")                                          \
    for (int i_ = 0; i_ < E_; ++i_) {                          \
      int ti_ = (cnt[i_] + 255) >> 8;                          \
      if ((ml) >= b_ && (ml) < b_ + ti_) {                     \
        e = i_; mt = (ml) - b_; Ne = cnt[i_]; }                \
      b_ += ti_; } }

// ---------------- workspace layout (bytes) ----------------
// xb     : T*D bf16     =  8,388,608  @ 0
// a_buf  : E*T*H bf16   = 33,554,432  @ 8,388,608
// lists  : E*T int      =     65,536  @ 41,943,040
// gates  : T*K f32      =     16,384  @ 42,008,576
// counts : E int        =         32  @ 42,024,960

__global__ __launch_bounds__(256) void init_kernel(
    const float* __restrict__ bias, float* __restrict__ out, int* __restrict__ counts)
{
  int idx = blockIdx.x * 256 + threadIdx.x;          // one float4 of out
  if (blockIdx.x == 0 && threadIdx.x < E_) counts[threadIdx.x] = 0;
  if (idx == 0) out[(size_t)T_ * D_] = 0.0f;         // router aux loss (eval mode)
  int dq = idx & (D_ / 4 - 1);
  f32x4 b = *(const f32x4*)(bias + dq * 4);
  *(f32x4*)(out + (size_t)idx * 4) = b;
}

// one block per token: logits, top-2 + softmax, build expert lists, x -> bf16
__global__ __launch_bounds__(256) void router_kernel(
    const float* __restrict__ x, const float* __restrict__ wg,
    u16* __restrict__ xb, int* __restrict__ lists, float* __restrict__ gates,
    int* __restrict__ counts)
{
  int t = blockIdx.x;
  int tid = threadIdx.x;
  const float* xr = x + (size_t)t * D_;
  float acc[E_];
#pragma unroll
  for (int e = 0; e < E_; ++e) acc[e] = 0.f;
#pragma unroll
  for (int i = 0; i < D_ / 256; ++i) {
    int d = tid + 256 * i;
    float xv = xr[d];
    xb[(size_t)t * D_ + d] = (u16)f2bf(xv);
#pragma unroll
    for (int e = 0; e < E_; ++e) acc[e] += xv * wg[e * D_ + d];
  }
#pragma unroll
  for (int off = 32; off >= 1; off >>= 1)
#pragma unroll
    for (int e = 0; e < E_; ++e) acc[e] += __shfl_down(acc[e], off);

  __shared__ float red[4][E_];
  int w = tid >> 6, lane = tid & 63;
  if (lane == 0)
#pragma unroll
    for (int e = 0; e < E_; ++e) red[w][e] = acc[e];
  __syncthreads();
  if (tid == 0) {
    float v0 = -1e30f, v1 = -1e30f; int e0 = 0, e1 = 0;
#pragma unroll
    for (int e = 0; e < E_; ++e) {
      float v = red[0][e] + red[1][e] + red[2][e] + red[3][e];
      if (v > v0)      { v1 = v0; e1 = e0; v0 = v; e0 = e; }
      else if (v > v1) { v1 = v;  e1 = e; }
    }
    float g1 = expf(v1 - v0);
    float inv = 1.f / (1.f + g1);
    float g0 = inv; g1 *= inv;
    int s0 = atomicAdd(&counts[e0], 1);
    lists[e0 * T_ + s0] = t * 2 + 0;
    gates[t * 2 + 0] = g0;
    int s1 = atomicAdd(&counts[e1], 1);
    lists[e1 * T_ + s1] = t * 2 + 1;
    gates[t * 2 + 1] = g1;
  }
}

// grouped GEMM1 + SiLU-GLU. Tile: 256 token-rows x 128 B-rows (h1/h2
// interleaved per 16). 8 waves = 4m x 2n of 64x64 -> 32 MFMA / 16 ds_read
// per wave-K-step (FLOP/LDS-byte maximized; kernel is LDS-pipe-bound at
// the pinned low clock). 1 block/CU, 256 blocks, XCD-chunked tiles.
__global__ __launch_bounds__(512, 2) void gemm1_kernel(
    const u16* __restrict__ xb, const float* __restrict__ w_in,
    const int* __restrict__ lists, const int* __restrict__ counts,
    u16* __restrict__ a_buf)
{
  __shared__ __align__(16) u16 As[2][256 * 64];   // 64 KB
  __shared__ __align__(16) u16 Bs[2][128 * 64];   // 32 KB -> 96 KB total

  int cnt[E_];
#pragma unroll
  for (int i = 0; i < E_; ++i) cnt[i] = counts[i];
  int mt_total = 0;
#pragma unroll
  for (int i = 0; i < E_; ++i) mt_total += (cnt[i] + 255) >> 8;
  const int NN1 = 2 * H_ / 128;                   // 16 n-tiles per m-tile
  int total = mt_total * NN1;
  int chunk = (total + 7) >> 3;                   // tiles per XCD

  int tid = threadIdx.x, w = tid >> 6, lane = tid & 63;
  int swzc = ((lane & 7) ^ (lane >> 3)) * 8;      // pre-swizzled source chunk
  int sr = tid >> 3;                              // A staging row base (0..63)
  int brow = tid >> 2, bc = (tid & 3) * 2;        // B staging: row 0..127, chunks bc,bc+1
  int wr = (w >> 1) * 64, wcB = (w & 1) * 64, lrow = lane & 15, g = lane >> 4;
  int lcol = lane & 15, lr4 = (lane >> 4) * 4;

  int xcd = blockIdx.x & 7, bslot = blockIdx.x >> 3;   // 32 block-slots per XCD

  for (int sl = bslot; sl < chunk; sl += 32) {
    int t = xcd * chunk + sl;
    if (t >= total) break;
    int ml = t / NN1, n = t % NN1;
    int e = 0, mt = 0, Ne = 0;
    FIND_EXPERT(ml, cnt, e, mt, Ne);

    const u16* ap[4];
#pragma unroll
    for (int i = 0; i < 4; ++i) {
      int gr = mt * 256 + 32 * w + 8 * i + (lane >> 3);
      if (gr >= Ne) gr = Ne - 1;
      ap[i] = xb + (size_t)(lists[e * T_ + gr] >> 1) * D_ + swzc;
    }
    // B row r (0..127) -> w_in row: h-col n*64 + (r>>5)*16 + (r&15), matrix (r>>4)&1
    int o = n * 64 + ((brow >> 4) & 1) * H_ + (brow >> 5) * 16 + (brow & 15);
    const float* bp = w_in + (size_t)e * (2 * H_) * D_ + (size_t)o * D_ + bc * 8;

    f32x4 acc[4][4];
#pragma unroll
    for (int m = 0; m < 4; ++m)
#pragma unroll
      for (int nn = 0; nn < 4; ++nn) acc[m][nn] = (f32x4){0.f, 0.f, 0.f, 0.f};

    f32x4 bl[4];
#define LOADS1(K) { _Pragma("unroll") for (int j = 0; j < 4; ++j) \
                      bl[j] = *(const f32x4*)(bp + (K) + j * 4); \
                    _Pragma("unroll") for (int i = 0; i < 4; ++i) \
                      gload16(ap[i] + (K), &As[(K) ? !((K/BK) & 1) : 0][(32 * w + 8 * i) * 64]); }
    // prologue
    { _Pragma("unroll") for (int j = 0; j < 4; ++j) bl[j] = *(const f32x4*)(bp + j * 4);
      _Pragma("unroll") for (int i = 0; i < 4; ++i) gload16(ap[i], &As[0][(32 * w + 8 * i) * 64]); }
    *(s16x8*)(&Bs[0][slot(brow, bc)])     = cvt8(bl[0], bl[1]);
    *(s16x8*)(&Bs[0][slot(brow, bc + 1)]) = cvt8(bl[2], bl[3]);
    __syncthreads();

    const int NT = D_ / BK;   // 32
    for (int kt = 0; kt < NT; ++kt) {
      int cur = kt & 1;
      if (kt + 1 < NT) {
        int k = (kt + 1) * BK;
#pragma unroll
        for (int j = 0; j < 4; ++j) bl[j] = *(const f32x4*)(bp + k + j * 4);
#pragma unroll
        for (int i = 0; i < 4; ++i) gload16(ap[i] + k, &As[cur ^ 1][(32 * w + 8 * i) * 64]);
      }
#pragma unroll
      for (int ks = 0; ks < 2; ++ks) {
        int ch = ks * 4 + g;
        s16x8 af[4], bf[4];
#pragma unroll
        for (int m = 0; m < 4; ++m) af[m] = *(const s16x8*)(&As[cur][slot(wr + m * 16 + lrow, ch)]);
#pragma unroll
        for (int nn = 0; nn < 4; ++nn) bf[nn] = *(const s16x8*)(&Bs[cur][slot(wcB + nn * 16 + lrow, ch)]);
#pragma unroll
        for (int m = 0; m < 4; ++m)
#pragma unroll
          for (int nn = 0; nn < 4; ++nn)
            acc[m][nn] = __builtin_amdgcn_mfma_f32_16x16x32_bf16(af[m], bf[nn], acc[m][nn], 0, 0, 0);
      }
      if (kt + 1 < NT) {
        *(s16x8*)(&Bs[cur ^ 1][slot(brow, bc)])     = cvt8(bl[0], bl[1]);  // waits B only (A in flight)
        *(s16x8*)(&Bs[cur ^ 1][slot(brow, bc + 1)]) = cvt8(bl[2], bl[3]);
      }
      __syncthreads();
    }
    // epilogue: acc[m][even]=h1, acc[m][odd]=h2 (same lane/row) -> a = silu(h1)*h2
#pragma unroll
    for (int m = 0; m < 4; ++m)
#pragma unroll
      for (int q = 0; q < 4; ++q) {
        int row = mt * 256 + wr + m * 16 + lr4 + q;
        if (row < Ne) {
#pragma unroll
          for (int n2 = 0; n2 < 2; ++n2) {
            float h1 = acc[m][n2 * 2][q], h2 = acc[m][n2 * 2 + 1][q];
            float a = (h1 / (1.f + __expf(-h1))) * h2;
            int col = n * 64 + ((w & 1) * 2 + n2) * 16 + lcol;
            a_buf[((size_t)e * T_ + row) * H_ + col] = (u16)f2bf(a);
          }
        }
      }
  }
}

// grouped GEMM2: out[t] += gate * (a_row . w_out[e]^T). Tile: 256 x 128 d-cols.
__global__ __launch_bounds__(512, 2) void gemm2_kernel(
    const u16* __restrict__ a_buf, const float* __restrict__ w_out,
    const int* __restrict__ lists, const int* __restrict__ counts,
    const float* __restrict__ gates, float* __restrict__ out)
{
  __shared__ __align__(16) u16 As[2][256 * 64];
  __shared__ __align__(16) u16 Bs[2][128 * 64];

  int cnt[E_];
#pragma unroll
  for (int i = 0; i < E_; ++i) cnt[i] = counts[i];
  int mt_total = 0;
#pragma unroll
  for (int i = 0; i < E_; ++i) mt_total += (cnt[i] + 255) >> 8;
  const int NN2 = D_ / 128;                       // 16
  int total = mt_total * NN2;
  int chunk = (total + 7) >> 3;

  int tid = threadIdx.x, w = tid >> 6, lane = tid & 63;
  int swzc = ((lane & 7) ^ (lane >> 3)) * 8;
  int brow = tid >> 2, bc = (tid & 3) * 2;
  int wr = (w >> 1) * 64, wcB = (w & 1) * 64, lrow = lane & 15, g = lane >> 4;
  int lcol = lane & 15, lr4 = (lane >> 4) * 4;

  int xcd = blockIdx.x & 7, bslot = blockIdx.x >> 3;

  for (int sl = bslot; sl < chunk; sl += 32) {
    int t = xcd * chunk + sl;
    if (t >= total) break;
    int ml = t / NN2, n = t % NN2;
    int e = 0, mt = 0, Ne = 0;
    FIND_EXPERT(ml, cnt, e, mt, Ne);

    const u16* ap[4];
#pragma unroll
    for (int i = 0; i < 4; ++i) {
      int gr = mt * 256 + 32 * w + 8 * i + (lane >> 3);
      if (gr >= Ne) gr = Ne - 1;
      ap[i] = a_buf + ((size_t)e * T_ + gr) * H_ + swzc;
    }
    const float* bp = w_out + (size_t)e * D_ * H_ + (size_t)(n * 128 + brow) * H_ + bc * 8;

    f32x4 acc[4][4];
#pragma unroll
    for (int m = 0; m < 4; ++m)
#pragma unroll
      for (int nn = 0; nn < 4; ++nn) acc[m][nn] = (f32x4){0.f, 0.f, 0.f, 0.f};

    f32x4 bl[4];
    { _Pragma("unroll") for (int j = 0; j < 4; ++j) bl[j] = *(const f32x4*)(bp + j * 4);
      _Pragma("unroll") for (int i = 0; i < 4; ++i) gload16(ap[i], &As[0][(32 * w + 8 * i) * 64]); }
    *(s16x8*)(&Bs[0][slot(brow, bc)])     = cvt8(bl[0], bl[1]);
    *(s16x8*)(&Bs[0][slot(brow, bc + 1)]) = cvt8(bl[2], bl[3]);
    __syncthreads();

    const int NT = H_ / BK;   // 16
    for (int kt = 0; kt < NT; ++kt) {
      int cur = kt & 1;
      if (kt + 1 < NT) {
        int k = (kt + 1) * BK;
#pragma unroll
        for (int j = 0; j < 4; ++j) bl[j] = *(const f32x4*)(bp + k + j * 4);
#pragma unroll
        for (int i = 0; i < 4; ++i) gload16(ap[i] + k, &As[cur ^ 1][(32 * w + 8 * i) * 64]);
      }
#pragma unroll
      for (int ks = 0; ks < 2; ++ks) {
        int ch = ks * 4 + g;
        s16x8 af[4], bf[4];
#pragma unroll
        for (int m = 0; m < 4; ++m) af[m] = *(const s16x8*)(&As[cur][slot(wr + m * 16 + lrow, ch)]);
#pragma unroll
        for (int nn = 0; nn < 4; ++nn) bf[nn] = *(const s16x8*)(&Bs[cur][slot(wcB + nn * 16 + lrow, ch)]);
#pragma unroll
        for (int m = 0; m < 4; ++m)
#pragma unroll
          for (int nn = 0; nn < 4; ++nn)
            acc[m][nn] = __builtin_amdgcn_mfma_f32_16x16x32_bf16(af[m], bf[nn], acc[m][nn], 0, 0, 0);
      }
      if (kt + 1 < NT) {
        *(s16x8*)(&Bs[cur ^ 1][slot(brow, bc)])     = cvt8(bl[0], bl[1]);
        *(s16x8*)(&Bs[cur ^ 1][slot(brow, bc + 1)]) = cvt8(bl[2], bl[3]);
      }
      __syncthreads();
    }
#pragma unroll
    for (int m = 0; m < 4; ++m)
#pragma unroll
      for (int q = 0; q < 4; ++q) {
        int row = mt * 256 + wr + m * 16 + lr4 + q;
        if (row < Ne) {
          int p = lists[e * T_ + row];
          float gt = gates[p];
          int tok = p >> 1;
#pragma unroll
          for (int nn = 0; nn < 4; ++nn)
            atomicAdd(&out[(size_t)tok * D_ + n * 128 + wcB + nn * 16 + lcol], gt * acc[m][nn][q]);
        }
      }
  }
}

extern "C" void kernel_launch(void* const* d_in, const int* in_sizes, int n_in,
                              void* d_out, int out_size, void* d_ws, size_t ws_size,
                              hipStream_t stream)
{
  const float* x      = (const float*)d_in[0];
  const float* w_gate = (const float*)d_in[1];
  const float* w_in   = (const float*)d_in[2];
  const float* w_out  = (const float*)d_in[3];
  const float* bias   = (const float*)d_in[4];
  float* out = (float*)d_out;

  char* ws = (char*)d_ws;
  u16*   xb     = (u16*)(ws);
  u16*   a_buf  = (u16*)(ws + 8388608);
  int*   lists  = (int*)(ws + 41943040);
  float* gates  = (float*)(ws + 42008576);
  int*   counts = (int*)(ws + 42024960);

  init_kernel<<<T_ * D_ / 4 / 256, 256, 0, stream>>>(bias, out, counts);
  router_kernel<<<T_, 256, 0, stream>>>(x, w_gate, xb, lists, gates, counts);
  gemm1_kernel<<<256, 512, 0, stream>>>(xb, w_in, lists, counts, a_buf);
  gemm2_kernel<<<256, 512, 0, stream>>>(a_buf, w_out, lists, counts, gates, out);
}

// Round 7
// 231.650 us; speedup vs baseline: 1.1474x; 1.1474x over previous
//
#include <hip/hip_runtime.h>
#include <hip/hip_bf16.h>

#define E_    8
#define D_    2048
#define H_    1024
#define T_    2048   // B*L tokens
#define BK    64

using u16   = unsigned short;
using s16x8 = __attribute__((ext_vector_type(8))) short;
using f32x4 = __attribute__((ext_vector_type(4))) float;

#define WAITVM(N) asm volatile("s_waitcnt vmcnt(" #N ")" ::: "memory")
#define LGKM0     asm volatile("s_waitcnt lgkmcnt(0)" ::: "memory")
#define SB0       __builtin_amdgcn_sched_barrier(0)

__device__ __forceinline__ short f2bf(float f) {
  __hip_bfloat16 h = __float2bfloat16(f);          // HW v_cvt (RNE)
  return __builtin_bit_cast(short, h);
}
__device__ __forceinline__ s16x8 cvt8(f32x4 a, f32x4 b) {
  s16x8 o;
  o[0]=f2bf(a.x); o[1]=f2bf(a.y); o[2]=f2bf(a.z); o[3]=f2bf(a.w);
  o[4]=f2bf(b.x); o[5]=f2bf(b.y); o[6]=f2bf(b.z); o[7]=f2bf(b.w);
  return o;
}
// swizzled LDS slot (elem index) for (row, 8-elem chunk) in a [*][64] bf16 tile
__device__ __forceinline__ int slot(int r, int c) { return r * 64 + ((c ^ (r & 7)) << 3); }

__device__ __forceinline__ void gload16(const void* g, void* l) {
  __builtin_amdgcn_global_load_lds((const __attribute__((address_space(1))) void*)g,
                                   (__attribute__((address_space(3))) void*)l, 16, 0, 0);
}

// find (e, mt, Ne) for linear m-tile index ml; registers only (unrolled)
#define FIND_EXPERT(ml, cnt, e, mt, Ne, RND, SH)               \
  { int b_ = 0;                                                \
    _Pragma("unroll")                                          \
    for (int i_ = 0; i_ < E_; ++i_) {                          \
      int ti_ = (cnt[i_] + RND) >> SH;                         \
      if ((ml) >= b_ && (ml) < b_ + ti_) {                     \
        e = i_; mt = (ml) - b_; Ne = cnt[i_]; }                \
      b_ += ti_; } }

// ---------------- workspace layout (bytes) ----------------
// xb     : T*D bf16     =  8,388,608  @ 0
// a_buf  : E*T*H bf16   = 33,554,432  @ 8,388,608
// lists  : E*T int      =     65,536  @ 41,943,040
// gates  : T*K f32      =     16,384  @ 42,008,576
// counts : E int        =         32  @ 42,024,960

__global__ __launch_bounds__(256) void init_kernel(
    const float* __restrict__ bias, float* __restrict__ out, int* __restrict__ counts)
{
  int idx = blockIdx.x * 256 + threadIdx.x;          // one float4 of out
  if (blockIdx.x == 0 && threadIdx.x < E_) counts[threadIdx.x] = 0;
  if (idx == 0) out[(size_t)T_ * D_] = 0.0f;         // router aux loss (eval mode)
  int dq = idx & (D_ / 4 - 1);
  f32x4 b = *(const f32x4*)(bias + dq * 4);
  *(f32x4*)(out + (size_t)idx * 4) = b;
}

// one block per token: logits, top-2 + softmax, build expert lists, x -> bf16
__global__ __launch_bounds__(256) void router_kernel(
    const float* __restrict__ x, const float* __restrict__ wg,
    u16* __restrict__ xb, int* __restrict__ lists, float* __restrict__ gates,
    int* __restrict__ counts)
{
  int t = blockIdx.x;
  int tid = threadIdx.x;
  const float* xr = x + (size_t)t * D_;
  float acc[E_];
#pragma unroll
  for (int e = 0; e < E_; ++e) acc[e] = 0.f;
#pragma unroll
  for (int i = 0; i < D_ / 256; ++i) {
    int d = tid + 256 * i;
    float xv = xr[d];
    xb[(size_t)t * D_ + d] = (u16)f2bf(xv);
#pragma unroll
    for (int e = 0; e < E_; ++e) acc[e] += xv * wg[e * D_ + d];
  }
#pragma unroll
  for (int off = 32; off >= 1; off >>= 1)
#pragma unroll
    for (int e = 0; e < E_; ++e) acc[e] += __shfl_down(acc[e], off);

  __shared__ float red[4][E_];
  int w = tid >> 6, lane = tid & 63;
  if (lane == 0)
#pragma unroll
    for (int e = 0; e < E_; ++e) red[w][e] = acc[e];
  __syncthreads();
  if (tid == 0) {
    float v0 = -1e30f, v1 = -1e30f; int e0 = 0, e1 = 0;
#pragma unroll
    for (int e = 0; e < E_; ++e) {
      float v = red[0][e] + red[1][e] + red[2][e] + red[3][e];
      if (v > v0)      { v1 = v0; e1 = e0; v0 = v; e0 = e; }
      else if (v > v1) { v1 = v;  e1 = e; }
    }
    float g1 = expf(v1 - v0);
    float inv = 1.f / (1.f + g1);
    float g0 = inv; g1 *= inv;
    int s0 = atomicAdd(&counts[e0], 1);
    lists[e0 * T_ + s0] = t * 2 + 0;
    gates[t * 2 + 0] = g0;
    int s1 = atomicAdd(&counts[e1], 1);
    lists[e1 * T_ + s1] = t * 2 + 1;
    gates[t * 2 + 1] = g1;
  }
}

// grouped GEMM1 + SiLU-GLU, counted-vmcnt pipeline (T3+T4+T5).
// Tile 256 rows x 128 B-rows (64 h1 + 64 h2 cols, paired per wave).
// A: triple-buffered LDS via global_load_lds, depth-2 prefetch.
// B: fp32->reg->cvt->ds_write, double-buffered. ONE raw barrier per K-tile,
// steady-state vmcnt floor = 4 (next-next A-tile always in flight).
__global__ __launch_bounds__(512, 1) void gemm1_kernel(
    const u16* __restrict__ xb, const float* __restrict__ w_in,
    const int* __restrict__ lists, const int* __restrict__ counts,
    u16* __restrict__ a_buf)
{
  __shared__ __align__(16) u16 As[3][256 * 64];   // 96 KB
  __shared__ __align__(16) u16 Bs[2][128 * 64];   // 32 KB -> 128 KB total

  int cnt[E_];
#pragma unroll
  for (int i = 0; i < E_; ++i) cnt[i] = counts[i];
  int mt_total = 0;
#pragma unroll
  for (int i = 0; i < E_; ++i) mt_total += (cnt[i] + 255) >> 8;
  int total = mt_total * 16;                      // 16 n-tiles (128 B-rows each)
  int chunk = (total + 7) >> 3;

  int tid = threadIdx.x, w = tid >> 6, lane = tid & 63;
  int swzc = ((lane & 7) ^ (lane >> 3)) * 8;      // pre-swizzled A source chunk
  int brow = tid >> 2, bc = (tid & 3) * 2;        // B staging: row, chunk pair
  int wr = (w >> 2) * 128, wc = (w & 3) * 32, lrow = lane & 15, g = lane >> 4;
  int lcol = lane & 15, lr4 = (lane >> 4) * 4;
  int xcd = blockIdx.x & 7, bslot = blockIdx.x >> 3;

  for (int sl = bslot; sl < chunk; sl += 32) {
    int t = xcd * chunk + sl;
    if (t >= total) break;
    int ml = t >> 4, n = t & 15;
    int e = 0, mt = 0, Ne = 0;
    FIND_EXPERT(ml, cnt, e, mt, Ne, 255, 8);

    const u16* ap[4];
#pragma unroll
    for (int i = 0; i < 4; ++i) {
      int gr = mt * 256 + 32 * w + 8 * i + (lane >> 3);
      if (gr >= Ne) gr = Ne - 1;
      ap[i] = xb + (size_t)(lists[e * T_ + gr] >> 1) * D_ + swzc;
    }
    // B row r (0..127): h-col = n*64 + (r>>5)*16 + (r&15); h1/h2 = (r>>4)&1
    int o = n * 64 + ((brow >> 4) & 1) * H_ + (brow >> 5) * 16 + (brow & 15);
    const float* bp = w_in + (size_t)e * (2 * H_) * D_ + (size_t)o * D_ + bc * 8;

    f32x4 acc[8][2];
#pragma unroll
    for (int m = 0; m < 8; ++m) { acc[m][0] = (f32x4){0,0,0,0}; acc[m][1] = (f32x4){0,0,0,0}; }
    f32x4 bl[4];

    // ---- prologue: B0 loads, A0/A1 gloads; drain B0 only; publish As[0],Bs[0]
#pragma unroll
    for (int j = 0; j < 4; ++j) bl[j] = *(const f32x4*)(bp + j * 4);
    SB0;
#pragma unroll
    for (int i = 0; i < 4; ++i) gload16(ap[i], &As[0][(32 * w + 8 * i) * 64]);
    SB0;
#pragma unroll
    for (int i = 0; i < 4; ++i) gload16(ap[i] + BK, &As[1][(32 * w + 8 * i) * 64]);
    SB0;
    WAITVM(8);  SB0;                               // B0 done; A0,A1 in flight
    *(s16x8*)(&Bs[0][slot(brow, bc)])     = cvt8(bl[0], bl[1]);
    *(s16x8*)(&Bs[0][slot(brow, bc + 1)]) = cvt8(bl[2], bl[3]);
    SB0;
#pragma unroll
    for (int j = 0; j < 4; ++j) bl[j] = *(const f32x4*)(bp + BK + j * 4);
    SB0;
    WAITVM(8);  SB0;                               // drains A0; A1,B1 in flight
    LGKM0;
    __builtin_amdgcn_s_barrier();

    const int NT = D_ / BK;                        // 32
    for (int kt = 0; kt < NT; ++kt) {
      int cur = kt % 3;
      if (kt + 2 < NT) {
        int wrt = cur + 2; if (wrt >= 3) wrt -= 3;
        int k2 = (kt + 2) * BK;
        SB0;
#pragma unroll
        for (int i = 0; i < 4; ++i) gload16(ap[i] + k2, &As[wrt][(32 * w + 8 * i) * 64]);
        SB0;
      }
#pragma unroll
      for (int ks = 0; ks < 2; ++ks) {
        int ch = ks * 4 + g;
        s16x8 af[8], bf[2];
#pragma unroll
        for (int m = 0; m < 8; ++m) af[m] = *(const s16x8*)(&As[cur][slot(wr + m * 16 + lrow, ch)]);
        bf[0] = *(const s16x8*)(&Bs[kt & 1][slot(wc + lrow, ch)]);
        bf[1] = *(const s16x8*)(&Bs[kt & 1][slot(wc + 16 + lrow, ch)]);
        __builtin_amdgcn_s_setprio(1);
#pragma unroll
        for (int m = 0; m < 8; ++m)
#pragma unroll
          for (int nn = 0; nn < 2; ++nn)
            acc[m][nn] = __builtin_amdgcn_mfma_f32_16x16x32_bf16(af[m], bf[nn], acc[m][nn], 0, 0, 0);
        __builtin_amdgcn_s_setprio(0);
      }
      if (kt + 1 < NT) {
        if (kt + 2 < NT) { WAITVM(4); } else { WAITVM(0); }   // keep next-next A flying
        SB0;
        *(s16x8*)(&Bs[(kt + 1) & 1][slot(brow, bc)])     = cvt8(bl[0], bl[1]);
        *(s16x8*)(&Bs[(kt + 1) & 1][slot(brow, bc + 1)]) = cvt8(bl[2], bl[3]);
        SB0;
        if (kt + 2 < NT) {
          int k2 = (kt + 2) * BK;
#pragma unroll
          for (int j = 0; j < 4; ++j) bl[j] = *(const f32x4*)(bp + k2 + j * 4);
          SB0;
        }
        LGKM0;
        __builtin_amdgcn_s_barrier();              // publish As[kt+1], Bs[(kt+1)&1]
      }
    }
    LGKM0;
    __builtin_amdgcn_s_barrier();                  // protect LDS before next tile
    // epilogue: a = silu(h1)*h2 -> bf16 (wave owns 128 rows x 16 h-cols)
#pragma unroll
    for (int m = 0; m < 8; ++m)
#pragma unroll
      for (int q = 0; q < 4; ++q) {
        int row = mt * 256 + wr + m * 16 + lr4 + q;
        if (row < Ne) {
          float h1 = acc[m][0][q], h2 = acc[m][1][q];
          float a = (h1 / (1.f + __expf(-h1))) * h2;
          a_buf[((size_t)e * T_ + row) * H_ + n * 64 + (w & 3) * 16 + lcol] = (u16)f2bf(a);
        }
      }
  }
}

// grouped GEMM2: out[t] += gate * (a_row . w_out[e]^T), same pipeline.
// Tile 128 rows x 128 d-cols, 8 waves of 64x32, 80 KB LDS -> 2 blocks/CU.
__global__ __launch_bounds__(512, 2) void gemm2_kernel(
    const u16* __restrict__ a_buf, const float* __restrict__ w_out,
    const int* __restrict__ lists, const int* __restrict__ counts,
    const float* __restrict__ gates, float* __restrict__ out)
{
  __shared__ __align__(16) u16 As[3][128 * 64];   // 48 KB
  __shared__ __align__(16) u16 Bs[2][128 * 64];   // 32 KB -> 80 KB

  int cnt[E_];
#pragma unroll
  for (int i = 0; i < E_; ++i) cnt[i] = counts[i];
  int mt_total = 0;
#pragma unroll
  for (int i = 0; i < E_; ++i) mt_total += (cnt[i] + 127) >> 7;
  int total = mt_total * 16;                      // 16 n-tiles of 128 d-cols
  int chunk = (total + 7) >> 3;

  int tid = threadIdx.x, w = tid >> 6, lane = tid & 63;
  int swzc = ((lane & 7) ^ (lane >> 3)) * 8;
  int brow = tid >> 2, bc = (tid & 3) * 2;
  int wr = (w >> 2) * 64, wc = (w & 3) * 32, lrow = lane & 15, g = lane >> 4;
  int lcol = lane & 15, lr4 = (lane >> 4) * 4;
  int xcd = blockIdx.x & 7, bslot = blockIdx.x >> 3;   // 512 blocks: 64 slots/XCD

  for (int sl = bslot; sl < chunk; sl += 64) {
    int t = xcd * chunk + sl;
    if (t >= total) break;
    int ml = t >> 4, n = t & 15;
    int e = 0, mt = 0, Ne = 0;
    FIND_EXPERT(ml, cnt, e, mt, Ne, 127, 7);

    const u16* ap[2];
#pragma unroll
    for (int i = 0; i < 2; ++i) {
      int gr = mt * 128 + 16 * w + 8 * i + (lane >> 3);
      if (gr >= Ne) gr = Ne - 1;
      ap[i] = a_buf + ((size_t)e * T_ + gr) * H_ + swzc;
    }
    const float* bp = w_out + (size_t)e * D_ * H_ + (size_t)(n * 128 + brow) * H_ + bc * 8;

    f32x4 acc[4][2];
#pragma unroll
    for (int m = 0; m < 4; ++m) { acc[m][0] = (f32x4){0,0,0,0}; acc[m][1] = (f32x4){0,0,0,0}; }
    f32x4 bl[4];

    // ---- prologue
#pragma unroll
    for (int j = 0; j < 4; ++j) bl[j] = *(const f32x4*)(bp + j * 4);
    SB0;
#pragma unroll
    for (int i = 0; i < 2; ++i) gload16(ap[i], &As[0][(16 * w + 8 * i) * 64]);
    SB0;
#pragma unroll
    for (int i = 0; i < 2; ++i) gload16(ap[i] + BK, &As[1][(16 * w + 8 * i) * 64]);
    SB0;
    WAITVM(4);  SB0;                               // B0 done; A0,A1 (4) in flight
    *(s16x8*)(&Bs[0][slot(brow, bc)])     = cvt8(bl[0], bl[1]);
    *(s16x8*)(&Bs[0][slot(brow, bc + 1)]) = cvt8(bl[2], bl[3]);
    SB0;
#pragma unroll
    for (int j = 0; j < 4; ++j) bl[j] = *(const f32x4*)(bp + BK + j * 4);
    SB0;
    WAITVM(6);  SB0;                               // drains A0; A1,B1 in flight
    LGKM0;
    __builtin_amdgcn_s_barrier();

    const int NT = H_ / BK;                        // 16
    for (int kt = 0; kt < NT; ++kt) {
      int cur = kt % 3;
      if (kt + 2 < NT) {
        int wrt = cur + 2; if (wrt >= 3) wrt -= 3;
        int k2 = (kt + 2) * BK;
        SB0;
#pragma unroll
        for (int i = 0; i < 2; ++i) gload16(ap[i] + k2, &As[wrt][(16 * w + 8 * i) * 64]);
        SB0;
      }
#pragma unroll
      for (int ks = 0; ks < 2; ++ks) {
        int ch = ks * 4 + g;
        s16x8 af[4], bf[2];
#pragma unroll
        for (int m = 0; m < 4; ++m) af[m] = *(const s16x8*)(&As[cur][slot(wr + m * 16 + lrow, ch)]);
        bf[0] = *(const s16x8*)(&Bs[kt & 1][slot(wc + lrow, ch)]);
        bf[1] = *(const s16x8*)(&Bs[kt & 1][slot(wc + 16 + lrow, ch)]);
        __builtin_amdgcn_s_setprio(1);
#pragma unroll
        for (int m = 0; m < 4; ++m)
#pragma unroll
          for (int nn = 0; nn < 2; ++nn)
            acc[m][nn] = __builtin_amdgcn_mfma_f32_16x16x32_bf16(af[m], bf[nn], acc[m][nn], 0, 0, 0);
        __builtin_amdgcn_s_setprio(0);
      }
      if (kt + 1 < NT) {
        if (kt + 2 < NT) { WAITVM(2); } else { WAITVM(0); }
        SB0;
        *(s16x8*)(&Bs[(kt + 1) & 1][slot(brow, bc)])     = cvt8(bl[0], bl[1]);
        *(s16x8*)(&Bs[(kt + 1) & 1][slot(brow, bc + 1)]) = cvt8(bl[2], bl[3]);
        SB0;
        if (kt + 2 < NT) {
          int k2 = (kt + 2) * BK;
#pragma unroll
          for (int j = 0; j < 4; ++j) bl[j] = *(const f32x4*)(bp + k2 + j * 4);
          SB0;
        }
        LGKM0;
        __builtin_amdgcn_s_barrier();
      }
    }
    LGKM0;
    __builtin_amdgcn_s_barrier();
    // epilogue: atomic accumulate (bias pre-filled)
#pragma unroll
    for (int m = 0; m < 4; ++m)
#pragma unroll
      for (int q = 0; q < 4; ++q) {
        int row = mt * 128 + wr + m * 16 + lr4 + q;
        if (row < Ne) {
          int p = lists[e * T_ + row];
          float gt = gates[p];
          int tok = p >> 1;
#pragma unroll
          for (int nn = 0; nn < 2; ++nn)
            atomicAdd(&out[(size_t)tok * D_ + n * 128 + wc + nn * 16 + lcol], gt * acc[m][nn][q]);
        }
      }
  }
}

extern "C" void kernel_launch(void* const* d_in, const int* in_sizes, int n_in,
                              void* d_out, int out_size, void* d_ws, size_t ws_size,
                              hipStream_t stream)
{
  const float* x      = (const float*)d_in[0];
  const float* w_gate = (const float*)d_in[1];
  const float* w_in   = (const float*)d_in[2];
  const float* w_out  = (const float*)d_in[3];
  const float* bias   = (const float*)d_in[4];
  float* out = (float*)d_out;

  char* ws = (char*)d_ws;
  u16*   xb     = (u16*)(ws);
  u16*   a_buf  = (u16*)(ws + 8388608);
  int*   lists  = (int*)(ws + 41943040);
  float* gates  = (float*)(ws + 42008576);
  int*   counts = (int*)(ws + 42024960);

  init_kernel<<<T_ * D_ / 4 / 256, 256, 0, stream>>>(bias, out, counts);
  router_kernel<<<T_, 256, 0, stream>>>(x, w_gate, xb, lists, gates, counts);
  gemm1_kernel<<<256, 512, 0, stream>>>(xb, w_in, lists, counts, a_buf);
  gemm2_kernel<<<512, 512, 0, stream>>>(a_buf, w_out, lists, counts, gates, out);
}

// Round 8
// 226.814 us; speedup vs baseline: 1.1719x; 1.0213x over previous
//
#include <hip/hip_runtime.h>
#include <hip/hip_bf16.h>

#define E_    8
#define D_    2048
#define H_    1024
#define T_    2048   // B*L tokens
#define BK    64

using u16   = unsigned short;
using s16x8 = __attribute__((ext_vector_type(8))) short;
using f32x4 = __attribute__((ext_vector_type(4))) float;

#define WAITVM0 asm volatile("s_waitcnt vmcnt(0)" ::: "memory")

__device__ __forceinline__ short f2bf(float f) {
  __hip_bfloat16 h = __float2bfloat16(f);          // HW v_cvt (RNE)
  return __builtin_bit_cast(short, h);
}
// swizzled LDS slot (elem index) for (row, 8-elem chunk) in a [*][64] bf16 tile
__device__ __forceinline__ int slot(int r, int c) { return r * 64 + ((c ^ (r & 7)) << 3); }

__device__ __forceinline__ void gload16(const void* g, void* l) {
  __builtin_amdgcn_global_load_lds((const __attribute__((address_space(1))) void*)g,
                                   (__attribute__((address_space(3))) void*)l, 16, 0, 0);
}

// find (e, mt, Ne) for linear m-tile index ml (bm=128); registers only
#define FIND_EXPERT(ml, cnt, e, mt, Ne)                        \
  { int b_ = 0;                                                \
    _Pragma("unroll")                                          \
    for (int i_ = 0; i_ < E_; ++i_) {                          \
      int ti_ = (cnt[i_] + 127) >> 7;                          \
      if ((ml) >= b_ && (ml) < b_ + ti_) {                     \
        e = i_; mt = (ml) - b_; Ne = cnt[i_]; }                \
      b_ += ti_; } }

// ---------------- workspace layout (bytes) ----------------
// xb     : T*D bf16      =  8,388,608  @ 0
// a_buf  : E*T*H bf16    = 33,554,432  @ 8,388,608
// wb_in  : E*2H*D bf16   = 67,108,864  @ 41,943,040
// wb_out : E*D*H bf16    = 33,554,432  @ 109,051,904
// lists  : E*T int       =     65,536  @ 142,606,336
// gates  : T*K f32       =     16,384  @ 142,671,872
// counts : E int         =         32  @ 142,688,256

#define WIN_ELEMS  33554432   // E*2H*D
#define WTOT_ELEMS 50331648   // + E*D*H

// prep: per token -> router (top-2 + softmax + lists) + x->bf16 + out=bias;
// plus grid-strided fp32->bf16 conversion of both weight tensors.
__global__ __launch_bounds__(256) void prep_kernel(
    const float* __restrict__ x, const float* __restrict__ wg,
    const float* __restrict__ w_in, const float* __restrict__ w_out,
    const float* __restrict__ bias,
    u16* __restrict__ xb, u16* __restrict__ wb_in, u16* __restrict__ wb_out,
    int* __restrict__ lists, float* __restrict__ gates, int* __restrict__ counts,
    float* __restrict__ out)
{
  int t = blockIdx.x;
  int tid = threadIdx.x;

  // ---- weight conversion slice: 24576 contiguous elems per block
#pragma unroll
  for (int j = 0; j < 12; ++j) {
    int idx = t * 24576 + j * 2048 + tid * 8;
    const float* src; u16* dst;
    if (idx < WIN_ELEMS) { src = w_in + idx;  dst = wb_in + idx; }
    else                 { src = w_out + (idx - WIN_ELEMS); dst = wb_out + (idx - WIN_ELEMS); }
    f32x4 a = *(const f32x4*)(src);
    f32x4 b = *(const f32x4*)(src + 4);
    s16x8 o;
    o[0]=f2bf(a.x); o[1]=f2bf(a.y); o[2]=f2bf(a.z); o[3]=f2bf(a.w);
    o[4]=f2bf(b.x); o[5]=f2bf(b.y); o[6]=f2bf(b.z); o[7]=f2bf(b.w);
    *(s16x8*)dst = o;
  }

  // ---- out = bias for token row t (+ loss elem)
  {
    const float* bp = bias + tid * 8;
    f32x4 b0 = *(const f32x4*)(bp), b1 = *(const f32x4*)(bp + 4);
    *(f32x4*)(out + (size_t)t * D_ + tid * 8)     = b0;
    *(f32x4*)(out + (size_t)t * D_ + tid * 8 + 4) = b1;
    if (t == 0 && tid == 0) out[(size_t)T_ * D_] = 0.0f;
  }

  // ---- router for token t (+ x -> bf16)
  const float* xr = x + (size_t)t * D_;
  float acc[E_];
#pragma unroll
  for (int e = 0; e < E_; ++e) acc[e] = 0.f;
#pragma unroll
  for (int i = 0; i < D_ / 256; ++i) {
    int d = tid + 256 * i;
    float xv = xr[d];
    xb[(size_t)t * D_ + d] = (u16)f2bf(xv);
#pragma unroll
    for (int e = 0; e < E_; ++e) acc[e] += xv * wg[e * D_ + d];
  }
#pragma unroll
  for (int off = 32; off >= 1; off >>= 1)
#pragma unroll
    for (int e = 0; e < E_; ++e) acc[e] += __shfl_down(acc[e], off);

  __shared__ float red[4][E_];
  int w = tid >> 6, lane = tid & 63;
  if (lane == 0)
#pragma unroll
    for (int e = 0; e < E_; ++e) red[w][e] = acc[e];
  __syncthreads();
  if (tid == 0) {
    float v0 = -1e30f, v1 = -1e30f; int e0 = 0, e1 = 0;
#pragma unroll
    for (int e = 0; e < E_; ++e) {
      float v = red[0][e] + red[1][e] + red[2][e] + red[3][e];
      if (v > v0)      { v1 = v0; e1 = e0; v0 = v; e0 = e; }
      else if (v > v1) { v1 = v;  e1 = e; }
    }
    float g1 = expf(v1 - v0);
    float inv = 1.f / (1.f + g1);
    float g0 = inv; g1 *= inv;
    int s0 = atomicAdd(&counts[e0], 1);
    lists[e0 * T_ + s0] = t * 2 + 0;
    gates[t * 2 + 0] = g0;
    int s1 = atomicAdd(&counts[e1], 1);
    lists[e1 * T_ + s1] = t * 2 + 1;
    gates[t * 2 + 1] = g1;
  }
}

// grouped GEMM1 + SiLU-GLU, all-bf16 gload_lds staging.
// Tile: 128 token-rows x 128 B-rows (64 h1 + 64 h2 -> 64 h-cols).
// 8 waves (2m x 4n), wave = 64 rows x 32 B-cols. 64 KB LDS -> 2 blocks/CU.
// 512 tiles, XCD-chunked n-fastest (A-panel stays L2-resident).
__global__ __launch_bounds__(512, 2) void gemm1_kernel(
    const u16* __restrict__ xb, const u16* __restrict__ wb_in,
    const int* __restrict__ lists, const int* __restrict__ counts,
    u16* __restrict__ a_buf)
{
  __shared__ __align__(16) u16 As[2][128 * 64];   // 32 KB
  __shared__ __align__(16) u16 Bs[2][128 * 64];   // 32 KB

  int cnt[E_];
#pragma unroll
  for (int i = 0; i < E_; ++i) cnt[i] = counts[i];
  int mt_total = 0;
#pragma unroll
  for (int i = 0; i < E_; ++i) mt_total += (cnt[i] + 127) >> 7;
  int total = mt_total * 16;                      // 16 n-tiles of 64 h-cols
  int chunk = (total + 7) >> 3;

  int tid = threadIdx.x, w = tid >> 6, lane = tid & 63;
  int swzc = ((lane & 7) ^ (lane >> 3)) * 8;      // pre-swizzled source chunk
  int wr = (w >> 2) * 64, wc = (w & 3) * 32, lrow = lane & 15, g = lane >> 4;
  int lcol = lane & 15, lr4 = (lane >> 4) * 4;
  int xcd = blockIdx.x & 7, bslot = blockIdx.x >> 3;

  for (int sl = bslot; sl < chunk; sl += 64) {
    int t = xcd * chunk + sl;
    if (t >= total) break;
    int ml = t >> 4, n = t & 15;
    int e = 0, mt = 0, Ne = 0;
    FIND_EXPERT(ml, cnt, e, mt, Ne);

    // A: 2 gloads/thread cover local rows w*8+(lane>>3) and +64
    const u16* ap[2];
#pragma unroll
    for (int i = 0; i < 2; ++i) {
      int gr = mt * 128 + w * 8 + i * 64 + (lane >> 3);
      if (gr >= Ne) gr = Ne - 1;
      ap[i] = xb + (size_t)(lists[e * T_ + gr] >> 1) * D_ + swzc;
    }
    // B: rows br -> wb_in row o = n*64 + mat*H + (br>>5)*16 + (br&15)
    const u16* bp[2];
#pragma unroll
    for (int i = 0; i < 2; ++i) {
      int br = w * 8 + i * 64 + (lane >> 3);
      int o = n * 64 + ((br >> 4) & 1) * H_ + (br >> 5) * 16 + (br & 15);
      bp[i] = wb_in + (size_t)e * (2 * H_) * D_ + (size_t)o * D_ + swzc;
    }

    f32x4 acc[4][2];
#pragma unroll
    for (int m = 0; m < 4; ++m) { acc[m][0] = (f32x4){0,0,0,0}; acc[m][1] = (f32x4){0,0,0,0}; }

    // prologue: stage kt=0 into buf 0
#pragma unroll
    for (int i = 0; i < 2; ++i) {
      gload16(ap[i], &As[0][(w * 8 + i * 64) * 64]);
      gload16(bp[i], &Bs[0][(w * 8 + i * 64) * 64]);
    }
    WAITVM0;
    __syncthreads();

    const int NT = D_ / BK;                        // 32
    for (int kt = 0; kt < NT; ++kt) {
      int cur = kt & 1;
      if (kt + 1 < NT) {
        int k = (kt + 1) * BK;
#pragma unroll
        for (int i = 0; i < 2; ++i) {
          gload16(ap[i] + k, &As[cur ^ 1][(w * 8 + i * 64) * 64]);
          gload16(bp[i] + k, &Bs[cur ^ 1][(w * 8 + i * 64) * 64]);
        }
      }
#pragma unroll
      for (int ks = 0; ks < 2; ++ks) {
        int ch = ks * 4 + g;
        s16x8 af[4], bf[2];
#pragma unroll
        for (int m = 0; m < 4; ++m) af[m] = *(const s16x8*)(&As[cur][slot(wr + m * 16 + lrow, ch)]);
#pragma unroll
        for (int s = 0; s < 2; ++s)  bf[s] = *(const s16x8*)(&Bs[cur][slot(wc + s * 16 + lrow, ch)]);
#pragma unroll
        for (int m = 0; m < 4; ++m)
#pragma unroll
          for (int s = 0; s < 2; ++s)
            acc[m][s] = __builtin_amdgcn_mfma_f32_16x16x32_bf16(af[m], bf[s], acc[m][s], 0, 0, 0);
      }
      WAITVM0;                                     // next-buf loads landed
      __syncthreads();
    }
    // epilogue: a = silu(h1)*h2 -> bf16; wave owns 64 rows x 16 h-cols
#pragma unroll
    for (int m = 0; m < 4; ++m)
#pragma unroll
      for (int q = 0; q < 4; ++q) {
        int row = mt * 128 + wr + m * 16 + lr4 + q;
        if (row < Ne) {
          float h1 = acc[m][0][q], h2 = acc[m][1][q];
          float a = (h1 / (1.f + __expf(-h1))) * h2;
          a_buf[((size_t)e * T_ + row) * H_ + n * 64 + (w & 3) * 16 + lcol] = (u16)f2bf(a);
        }
      }
  }
}

// grouped GEMM2: out[t] += gate * (a_row . wb_out[e]^T), all-bf16 gloads.
// Tile: 128 rows x 128 d-cols, 8 waves (2m x 4n) of 64x32, 64 KB LDS.
__global__ __launch_bounds__(512, 2) void gemm2_kernel(
    const u16* __restrict__ a_buf, const u16* __restrict__ wb_out,
    const int* __restrict__ lists, const int* __restrict__ counts,
    const float* __restrict__ gates, float* __restrict__ out)
{
  __shared__ __align__(16) u16 As[2][128 * 64];
  __shared__ __align__(16) u16 Bs[2][128 * 64];

  int cnt[E_];
#pragma unroll
  for (int i = 0; i < E_; ++i) cnt[i] = counts[i];
  int mt_total = 0;
#pragma unroll
  for (int i = 0; i < E_; ++i) mt_total += (cnt[i] + 127) >> 7;
  int total = mt_total * 16;                      // 16 n-tiles of 128 d-cols
  int chunk = (total + 7) >> 3;

  int tid = threadIdx.x, w = tid >> 6, lane = tid & 63;
  int swzc = ((lane & 7) ^ (lane >> 3)) * 8;
  int wr = (w >> 2) * 64, wc = (w & 3) * 32, lrow = lane & 15, g = lane >> 4;
  int lcol = lane & 15, lr4 = (lane >> 4) * 4;
  int xcd = blockIdx.x & 7, bslot = blockIdx.x >> 3;

  for (int sl = bslot; sl < chunk; sl += 64) {
    int t = xcd * chunk + sl;
    if (t >= total) break;
    int ml = t >> 4, n = t & 15;
    int e = 0, mt = 0, Ne = 0;
    FIND_EXPERT(ml, cnt, e, mt, Ne);

    const u16* ap[2];
#pragma unroll
    for (int i = 0; i < 2; ++i) {
      int gr = mt * 128 + w * 8 + i * 64 + (lane >> 3);
      if (gr >= Ne) gr = Ne - 1;
      ap[i] = a_buf + ((size_t)e * T_ + gr) * H_ + swzc;
    }
    const u16* bp[2];
#pragma unroll
    for (int i = 0; i < 2; ++i) {
      int br = w * 8 + i * 64 + (lane >> 3);
      bp[i] = wb_out + (size_t)e * D_ * H_ + (size_t)(n * 128 + br) * H_ + swzc;
    }

    f32x4 acc[4][2];
#pragma unroll
    for (int m = 0; m < 4; ++m) { acc[m][0] = (f32x4){0,0,0,0}; acc[m][1] = (f32x4){0,0,0,0}; }

#pragma unroll
    for (int i = 0; i < 2; ++i) {
      gload16(ap[i], &As[0][(w * 8 + i * 64) * 64]);
      gload16(bp[i], &Bs[0][(w * 8 + i * 64) * 64]);
    }
    WAITVM0;
    __syncthreads();

    const int NT = H_ / BK;                        // 16
    for (int kt = 0; kt < NT; ++kt) {
      int cur = kt & 1;
      if (kt + 1 < NT) {
        int k = (kt + 1) * BK;
#pragma unroll
        for (int i = 0; i < 2; ++i) {
          gload16(ap[i] + k, &As[cur ^ 1][(w * 8 + i * 64) * 64]);
          gload16(bp[i] + k, &Bs[cur ^ 1][(w * 8 + i * 64) * 64]);
        }
      }
#pragma unroll
      for (int ks = 0; ks < 2; ++ks) {
        int ch = ks * 4 + g;
        s16x8 af[4], bf[2];
#pragma unroll
        for (int m = 0; m < 4; ++m) af[m] = *(const s16x8*)(&As[cur][slot(wr + m * 16 + lrow, ch)]);
#pragma unroll
        for (int s = 0; s < 2; ++s)  bf[s] = *(const s16x8*)(&Bs[cur][slot(wc + s * 16 + lrow, ch)]);
#pragma unroll
        for (int m = 0; m < 4; ++m)
#pragma unroll
          for (int s = 0; s < 2; ++s)
            acc[m][s] = __builtin_amdgcn_mfma_f32_16x16x32_bf16(af[m], bf[s], acc[m][s], 0, 0, 0);
      }
      WAITVM0;
      __syncthreads();
    }
    // epilogue: atomic accumulate (bias pre-filled by prep)
#pragma unroll
    for (int m = 0; m < 4; ++m)
#pragma unroll
      for (int q = 0; q < 4; ++q) {
        int row = mt * 128 + wr + m * 16 + lr4 + q;
        if (row < Ne) {
          int p = lists[e * T_ + row];
          float gt = gates[p];
          int tok = p >> 1;
#pragma unroll
          for (int s = 0; s < 2; ++s)
            atomicAdd(&out[(size_t)tok * D_ + n * 128 + wc + s * 16 + lcol], gt * acc[m][s][q]);
        }
      }
  }
}

extern "C" void kernel_launch(void* const* d_in, const int* in_sizes, int n_in,
                              void* d_out, int out_size, void* d_ws, size_t ws_size,
                              hipStream_t stream)
{
  const float* x      = (const float*)d_in[0];
  const float* w_gate = (const float*)d_in[1];
  const float* w_in   = (const float*)d_in[2];
  const float* w_out  = (const float*)d_in[3];
  const float* bias   = (const float*)d_in[4];
  float* out = (float*)d_out;

  char* ws = (char*)d_ws;
  u16*   xb     = (u16*)(ws);
  u16*   a_buf  = (u16*)(ws + 8388608);
  u16*   wb_in  = (u16*)(ws + 41943040);
  u16*   wb_out = (u16*)(ws + 109051904);
  int*   lists  = (int*)(ws + 142606336);
  float* gates  = (float*)(ws + 142671872);
  int*   counts = (int*)(ws + 142688256);

  hipMemsetAsync(counts, 0, E_ * sizeof(int), stream);
  prep_kernel<<<T_, 256, 0, stream>>>(x, w_gate, w_in, w_out, bias,
                                      xb, wb_in, wb_out, lists, gates, counts, out);
  gemm1_kernel<<<512, 512, 0, stream>>>(xb, wb_in, lists, counts, a_buf);
  gemm2_kernel<<<512, 512, 0, stream>>>(a_buf, wb_out, lists, counts, gates, out);
}